// Round 10
// baseline (164.507 us; speedup 1.0000x reference)
//
#include <hip/hip_runtime.h>
#include <hip/hip_bf16.h>
#include <math.h>

// B=1024, N=22, F_IN=32, T=32, K=3, CHEV=64, TIMEF=64
// x[b,n,f,t]: b-stride 22528, n-stride 1024, f-stride 32

typedef unsigned short u16;
typedef __attribute__((ext_vector_type(8))) short short8;
typedef __attribute__((ext_vector_type(16))) float f32x16;
typedef __attribute__((ext_vector_type(2))) float f32x2;

__device__ __forceinline__ float sigm(float v){ return 1.f/(1.f+expf(-v)); }

__device__ __forceinline__ u16 f2bf(float x){
  __hip_bfloat16 h = __float2bfloat16(x);
  return *reinterpret_cast<u16*>(&h);
}
__device__ __forceinline__ unsigned f2bf2(float lo, float hi){
  return (unsigned)f2bf(lo) | ((unsigned)f2bf(hi) << 16);
}

// ---------------- attnA: temporal attention (phases 1-7) + prep + supports ----------------
__global__ __launch_bounds__(512) void k_attnA(
    const float* __restrict__ x,
    const float* __restrict__ U1, const float* __restrict__ U2, const float* __restrict__ U3,
    const float* __restrict__ be, const float* __restrict__ Ve, const float* __restrict__ W1,
    const float* __restrict__ W3,
    float* __restrict__ smG, float* __restrict__ w1eG, float* __restrict__ xw3G,
    const float* __restrict__ emb, float* __restrict__ wsT,
    const float* __restrict__ Theta,
    const float* __restrict__ tw, const float* __restrict__ tb,
    const float* __restrict__ rw, const float* __restrict__ rb,
    u16* __restrict__ thA, u16* __restrict__ wA, float* __restrict__ wsB){
  __shared__ float xu1[1024];
  __shared__ float rhs_t[704];
  __shared__ float lhs_t[704];
  __shared__ float sigp[1024];
  __shared__ float Em[1024];
  __shared__ float sm[1024];
  __shared__ float xw3[704];
  __shared__ float w1e[32];

  int bid = blockIdx.x, tid = threadIdx.x;

  if (bid >= 1024){
    int pb = bid - 1024;
    if (pb < 41){
      // 32x32-fragment weight packing (R7 layout)
      int t2 = pb*512 + tid;
      if (t2 < 6144){
        int j = t2&7, l = (t2>>3)&63, slot = t2>>9;   // slot 0..11
        int fb = slot>>1, ch = slot&1;
        int hi = l>>5, r = l&31;
        int row = (fb < 4) ? (32 + 16*fb + 8*hi + j) : (16*(fb-4) + 8*hi + j);
        thA[t2] = f2bf(Theta[row*64 + 32*ch + r]);
      } else if (t2 < 20480){
        int e = t2 - 6144;
        int j = e&7, l = (e>>3)&63, slot = e>>9;      // slot 0..27
        int kb = slot>>1, oh = slot&1;
        int hi = l>>5, r = l&31;
        int k = 16*kb + 8*hi + j;
        int o = 32*oh + r;
        float v = (k < 192) ? tw[o*192 + (k&63)*3 + (k>>6)] : rw[o*32 + (k-192)];
        wA[e] = f2bf(v);
      } else if (t2 < 20544){
        int o = t2 - 20480; wsB[o] = tb[o] + rb[o];
      }
      return;
    }
    float* M   = &xu1[0];
    float* T1s = &sigp[0];
    for (int idx=tid; idx<484; idx+=512){
      int n = idx/22, m = idx - (idx/22)*22;
      float s = 0.f;
      for (int j=0;j<22;j++) s += emb[n*22+j]*emb[m*22+j];
      M[idx] = fmaxf(s, 0.f);
    }
    __syncthreads();
    if (tid < 22){
      float mx = -1e30f;
      for (int m=0;m<22;m++) mx = fmaxf(mx, M[tid*22+m]);
      float s = 0.f;
      for (int m=0;m<22;m++) s += expf(M[tid*22+m]-mx);
      float inv = 1.f/s;
      for (int m=0;m<22;m++) T1s[tid*22+m] = expf(M[tid*22+m]-mx)*inv;
    }
    __syncthreads();
    for (int idx=tid; idx<484; idx+=512){
      int n = idx/22, m = idx - (idx/22)*22;
      float s = 0.f;
      for (int p=0;p<22;p++) s += T1s[n*22+p]*T1s[p*22+m];
      wsT[idx]      = T1s[idx];
      wsT[484+idx]  = 2.f*s - ((n==m)?1.f:0.f);
    }
    return;
  }

  int b = bid;
  const float* xb = x + (size_t)b*22528;

  for (int idx=tid; idx<1024; idx+=512){
    float a=0.f;
    for (int n=0;n<22;n++) a = fmaf(xb[n*1024 + idx], U1[n], a);
    xu1[idx]=a;
  }
  for (int idx=tid; idx<704; idx+=512){
    int n = idx>>5, t = idx&31; float a=0.f, c=0.f;
    for (int f=0;f<32;f++){ float xv = xb[n*1024+f*32+t]; a = fmaf(U3[f],xv,a); c = fmaf(W3[f],xv,c); }
    rhs_t[idx]=a; xw3[idx]=c;
  }
  __syncthreads();
  for (int idx=tid; idx<704; idx+=512){
    int t = idx/22, n2 = idx - t*22; float a=0.f;
    for (int f=0;f<32;f++) a = fmaf(xu1[f*32+t], U2[f*22+n2], a);
    lhs_t[idx]=a;
  }
  __syncthreads();
  for (int idx=tid; idx<1024; idx+=512){
    int s = idx>>5, u = idx&31; float p=0.f;
    for (int n=0;n<22;n++) p = fmaf(lhs_t[s*22+n], rhs_t[n*32+u], p);
    sigp[idx] = sigm(p + be[idx]);
  }
  __syncthreads();
  for (int idx=tid; idx<1024; idx+=512){
    int t = idx>>5, u = idx&31; float a=0.f;
    for (int s2=0;s2<32;s2++) a = fmaf(Ve[t*32+s2], sigp[s2*32+u], a);
    Em[idx]=a;
  }
  __syncthreads();
  {
    int u = tid>>4, th = tid&15;
    float e0 = Em[(2*th)*32 + u], e1 = Em[(2*th+1)*32 + u];
    float mx = fmaxf(e0, e1);
    #pragma unroll
    for (int mask=1; mask<16; mask<<=1) mx = fmaxf(mx, __shfl_xor(mx, mask));
    float x0 = expf(e0-mx), x1 = expf(e1-mx);
    float s = x0 + x1;
    #pragma unroll
    for (int mask=1; mask<16; mask<<=1) s += __shfl_xor(s, mask);
    float inv = 1.f/s;
    sm[(2*th)*32 + u]   = x0*inv;
    sm[(2*th+1)*32 + u] = x1*inv;
  }
  __syncthreads();
  {
    int u = tid>>4, th = tid&15;
    float pw = fmaf(sm[u*32 + 2*th], W1[2*th], sm[u*32 + 2*th+1]*W1[2*th+1]);
    #pragma unroll
    for (int mask=1; mask<16; mask<<=1) pw += __shfl_xor(pw, mask);
    if (th==0) w1e[u] = pw;
  }
  __syncthreads();
  for (int idx=tid; idx<1024; idx+=512) smG[(size_t)b*1024 + idx] = sm[idx];
  for (int idx=tid; idx<704; idx+=512)  xw3G[(size_t)b*704 + idx] = xw3[idx];
  if (tid < 32) w1eG[b*32 + tid] = w1e[tid];
}

// ---------------- attnB: spatial attention (phases 8-13) -> snorm ----------------
__global__ __launch_bounds__(512) void k_attnB(
    const float* __restrict__ x,
    const float* __restrict__ W2, const float* __restrict__ bs, const float* __restrict__ Vs,
    const float* __restrict__ smG, const float* __restrict__ w1eG, const float* __restrict__ xw3G,
    float* __restrict__ snorm){
  __shared__ float sm[1024];
  __shared__ float xw3[704];
  __shared__ float w1e[32];
  __shared__ float lhsS[704];
  __shared__ float lhs2[704];
  __shared__ float rhsS[704];
  __shared__ float sig2[484];
  __shared__ float Sl[484];

  int b = blockIdx.x, tid = threadIdx.x;
  const float* xb = x + (size_t)b*22528;

  for (int idx=tid; idx<1024; idx+=512) sm[idx] = smG[(size_t)b*1024 + idx];
  for (int idx=tid; idx<704; idx+=512)  xw3[idx] = xw3G[(size_t)b*704 + idx];
  if (tid < 32) w1e[tid] = w1eG[b*32 + tid];
  __syncthreads();

  for (int idx=tid; idx<704; idx+=512){
    int n = idx>>5, f = idx&31;
    const float4* xp = (const float4*)(xb + n*1024 + f*32);
    const float4* wv = (const float4*)w1e;
    float a = 0.f;
    #pragma unroll
    for (int q=0;q<8;q++){
      float4 xv = xp[q], w4 = wv[q];
      a = fmaf(xv.x, w4.x, a); a = fmaf(xv.y, w4.y, a);
      a = fmaf(xv.z, w4.z, a); a = fmaf(xv.w, w4.w, a);
    }
    lhsS[idx]=a;
  }
  __syncthreads();
  for (int idx=tid; idx<704; idx+=512){
    int n = idx>>5, t = idx&31; float a=0.f;
    for (int f=0;f<32;f++) a = fmaf(lhsS[n*32+f], W2[f*32+t], a);
    lhs2[idx]=a;
  }
  for (int idx=tid; idx<704; idx+=512){
    int mm = idx>>5, t = idx&31; float a=0.f;
    for (int u=0;u<32;u++) a = fmaf(xw3[mm*32+u], sm[u*32+t], a);
    rhsS[idx]=a;
  }
  __syncthreads();
  for (int idx=tid; idx<484; idx+=512){
    int a_ = idx/22, l = idx - (idx/22)*22; float p=0.f;
    for (int t=0;t<32;t++) p = fmaf(lhs2[a_*32+t], rhsS[l*32+t], p);
    sig2[idx] = sigm(p + bs[idx]);
  }
  __syncthreads();
  for (int idx=tid; idx<484; idx+=512){
    int n = idx/22, l = idx - (idx/22)*22; float s=0.f;
    for (int mm=0;mm<22;mm++) s = fmaf(Vs[n*22+mm], sig2[mm*22+l], s);
    Sl[idx]=s;
  }
  __syncthreads();
  {
    int grp = tid>>5, nn = tid&31;
    for (int l = grp; l < 22; l += 16){
      float v = (nn<22) ? Sl[nn*22 + l] : -1e30f;
      float mx = v;
      #pragma unroll
      for (int mask=1; mask<32; mask<<=1) mx = fmaxf(mx, __shfl_xor(mx, mask));
      float e = (nn<22) ? expf(v-mx) : 0.f;
      float s = e;
      #pragma unroll
      for (int mask=1; mask<32; mask<<=1) s += __shfl_xor(s, mask);
      if (nn<22) snorm[(size_t)b*484 + nn*22 + l] = e*(1.f/s);
    }
  }
}

// ---------------- Fused m-pair (32x32x16 MFMA + asm-pinned weight prefetch) ----------------
// Phase A: float4 x loads, XOR-swizzled transposed LDS writes (R5/R7 proven).
// 32x32 MFMA halves per-block LDS b128 reads vs 16x16 (80 vs 160).
// Weight fragments loaded early and PINNED in VGPRs via asm so the compiler
// cannot sink them back to their use sites (R8 failure mode, VGPR stayed 40).
__global__ __launch_bounds__(256, 3) void k_fused(
    const float* __restrict__ x,
    const float* __restrict__ wsT, const float* __restrict__ snorm,
    const u16* __restrict__ thA, const u16* __restrict__ wA, const float* __restrict__ wsB,
    const float* __restrict__ lng, const float* __restrict__ lnb,
    float* __restrict__ out){
  __shared__ __align__(16) u16 GtU[2][32*72];   // G^T bf16 [t][8 col-blocks of 8], stride 72
  __shared__ __align__(16) u16 sgTU[2][34*72];  // sg^T bf16 [t+1][c], rows 0,33 zero
  __shared__ __align__(16) u16 xTU[2][32*40];   // x[m]^T bf16 [t][4 col-blocks of 8], stride 40
  __shared__ __align__(16) float ak4[22*4];     // [n][mi*2+k1]
  __shared__ float smm[2];

  int wg = blockIdx.x;
  int logical = (wg & 7)*1408 + (wg >> 3);      // 11264 = 8*1408 XCD swizzle
  int b = logical/11, mp = logical - b*11;
  int m0 = mp*2;
  int tid = threadIdx.x;
  const float* xb = x + (size_t)b*22528;

  int w = tid>>6, l = tid&63, hi = l>>5, lt = l&31;
  int mi_w = w>>1, ch = w&1;

  // ---- issue Phase B weight fragment loads now; pin before the A->B barrier ----
  short8 a_th[6];
  #pragma unroll
  for (int fb=0; fb<6; ++fb)
    a_th[fb] = *(const short8*)(thA + (size_t)(fb*2+ch)*512 + l*8);

  if (tid < 128){                                // zero sg pad rows 0, 33
    int mi = tid>>6, c = tid&63;
    sgTU[mi][c] = 0;
    sgTU[mi][33*72 + c] = 0;
  }
  if (tid < 88){
    int n = tid>>2, j = tid&3;                  // j = mi*2 + k1
    int mi = j>>1, k1 = j&1;
    int m = m0 + mi;
    ak4[tid] = wsT[k1*484 + n*22 + m] * snorm[(size_t)b*484 + n*22 + m];
  }
  if (tid < 2) smm[tid] = snorm[(size_t)b*484 + (m0+tid)*23];
  __syncthreads();

  // ---- Phase A: G[k1][f][t] = sum_n ak*x ; float4 loads, swizzled b16 writes ----
  {
    f32x2 acc[4][2];                             // [mi*2+k1][half]
    #pragma unroll
    for (int j=0;j<4;j++){ acc[j][0]=f32x2{0,0}; acc[j][1]=f32x2{0,0}; }
    const float4* x4 = (const float4*)xb;
    #pragma unroll 2
    for (int n=0;n<22;n++){
      float4 av = *(const float4*)&ak4[n*4];
      float4 xv = x4[n*256 + tid];
      f32x2 xlo = {xv.x, xv.y}, xhi2 = {xv.z, xv.w};
      f32x2 c0 = {av.x,av.x}, c1 = {av.y,av.y}, c2 = {av.z,av.z}, c3 = {av.w,av.w};
      acc[0][0] = __builtin_elementwise_fma(c0, xlo,  acc[0][0]);
      acc[0][1] = __builtin_elementwise_fma(c0, xhi2, acc[0][1]);
      acc[1][0] = __builtin_elementwise_fma(c1, xlo,  acc[1][0]);
      acc[1][1] = __builtin_elementwise_fma(c1, xhi2, acc[1][1]);
      acc[2][0] = __builtin_elementwise_fma(c2, xlo,  acc[2][0]);
      acc[2][1] = __builtin_elementwise_fma(c2, xhi2, acc[2][1]);
      acc[3][0] = __builtin_elementwise_fma(c3, xlo,  acc[3][0]);
      acc[3][1] = __builtin_elementwise_fma(c3, xhi2, acc[3][1]);
    }
    int f = tid>>3, t7 = tid&7, t0 = t7*4;
    int w4 = f>>3, f_low = f&7;
    int gcol0 = 8*((0*4 + w4) ^ t7) + f_low;
    int gcol1 = 8*((1*4 + w4) ^ t7) + f_low;
    int xcol  = 8*(w4 ^ (t7&3)) + f_low;
    #pragma unroll
    for (int mi=0;mi<2;mi++){
      float4 xm = ((const float4*)xb)[(m0+mi)*256 + tid];
      u16* xd = &xTU[mi][0];
      xd[(t0+0)*40 + xcol] = f2bf(xm.x);
      xd[(t0+1)*40 + xcol] = f2bf(xm.y);
      xd[(t0+2)*40 + xcol] = f2bf(xm.z);
      xd[(t0+3)*40 + xcol] = f2bf(xm.w);
      #pragma unroll
      for (int k1=0;k1<2;k1++){
        int j = mi*2 + k1;
        int gc = k1 ? gcol1 : gcol0;
        u16* gd = &GtU[mi][gc];
        gd[(t0+0)*72] = f2bf(acc[j][0][0]);
        gd[(t0+1)*72] = f2bf(acc[j][0][1]);
        gd[(t0+2)*72] = f2bf(acc[j][1][0]);
        gd[(t0+3)*72] = f2bf(acc[j][1][1]);
      }
    }
  }
  // pin thA fragments: force them resident in VGPRs before the barrier
  #pragma unroll
  for (int fb=0; fb<6; ++fb) asm volatile("" : "+v"(a_th[fb]));
  __syncthreads();

  int key8 = lt>>2;            // GtU read swizzle key
  int key4 = key8 & 3;         // xTU read swizzle key

  // ---- issue Phase C weight fragment loads; they drain at the B->C barrier ----
  short8 wk[14];
  #pragma unroll
  for (int kb=0; kb<14; ++kb)
    wk[kb] = *(const short8*)(wA + (size_t)(kb*2+ch)*512 + l*8);

  // ---- Phase B: sg[c][t] = relu( Theta12^T G + smm * Theta0^T x ), c-half = ch ----
  {
    f32x16 aG, aX;
    #pragma unroll
    for (int i=0;i<16;i++){ aG[i]=0.f; aX[i]=0.f; }
    const u16* gBase = &GtU[mi_w][lt*72];
    const u16* xBase = &xTU[mi_w][lt*40];
    #pragma unroll
    for (int fb=0; fb<4; ++fb){
      const short8* gp = (const short8*)(gBase + 8*((2*fb+hi)^key8));
      aG = __builtin_amdgcn_mfma_f32_32x32x16_bf16(a_th[fb], *gp, aG, 0,0,0);
    }
    #pragma unroll
    for (int fb=4; fb<6; ++fb){
      const short8* xp = (const short8*)(xBase + 8*((2*(fb-4)+hi)^key4));
      aX = __builtin_amdgcn_mfma_f32_32x32x16_bf16(a_th[fb], *xp, aX, 0,0,0);
    }
    float smv = smm[mi_w];
    u16* srow = &sgTU[mi_w][(1+lt)*72 + ch*32 + 4*hi];
    #pragma unroll
    for (int q=0;q<4;q++){
      float v0 = fmaxf(fmaf(smv, aX[4*q+0], aG[4*q+0]), 0.f);
      float v1 = fmaxf(fmaf(smv, aX[4*q+1], aG[4*q+1]), 0.f);
      float v2 = fmaxf(fmaf(smv, aX[4*q+2], aG[4*q+2]), 0.f);
      float v3 = fmaxf(fmaf(smv, aX[4*q+3], aG[4*q+3]), 0.f);
      uint2 pv; pv.x = f2bf2(v0,v1); pv.y = f2bf2(v2,v3);
      *(uint2*)&srow[8*q] = pv;
    }
  }
  // pin wA fragments before the barrier: loads must complete here, stay in VGPRs
  #pragma unroll
  for (int kb=0; kb<14; ++kb) asm volatile("" : "+v"(wk[kb]));
  __syncthreads();

  // ---- Phase C: y[o][t] = sum_k W[k][o]*B[k][t], K=224, o-half = ch ----
  f32x16 acc;
  #pragma unroll
  for (int i=0;i<16;i++) acc[i]=0.f;
  {
    #pragma unroll
    for (int kb=0; kb<12; ++kb){
      int dt = kb>>2, cq = kb&3;
      const short8* Bp = (const short8*)&sgTU[mi_w][(lt+dt)*72 + cq*16 + 8*hi];
      acc = __builtin_amdgcn_mfma_f32_32x32x16_bf16(wk[kb], *Bp, acc, 0,0,0);
    }
    #pragma unroll
    for (int kb=12; kb<14; ++kb){
      const short8* Bp = (const short8*)&xTU[mi_w][lt*40 + 8*((2*(kb-12)+hi)^key4)];
      acc = __builtin_amdgcn_mfma_f32_32x32x16_bf16(wk[kb], *Bp, acc, 0,0,0);
    }
  }

  // ---- Epilogue: bias + relu + LN over o (64) per t ----
  float y[16];
  float s1 = 0.f, s2 = 0.f;
  {
    const float4* wsB4 = (const float4*)wsB;
    #pragma unroll
    for (int q=0;q<4;q++){
      float4 bq = wsB4[8*ch + 2*q + hi];
      float bb[4] = {bq.x, bq.y, bq.z, bq.w};
      #pragma unroll
      for (int e=0;e<4;e++){
        float v = fmaxf(acc[4*q+e] + bb[e], 0.f);
        y[4*q+e] = v;
        s1 += v;
        s2 = fmaf(v, v, s2);
      }
    }
  }
  s1 += __shfl_xor(s1, 32);
  s2 += __shfl_xor(s2, 32);
  float* p1 = (float*)&GtU[0][0];    // overlay (GtU dead after Phase B barrier)
  float* p2 = p1 + 128;
  if (l < 32){
    p1[(mi_w*32 + lt)*2 + ch] = s1;
    p2[(mi_w*32 + lt)*2 + ch] = s2;
  }
  __syncthreads();
  f32x2 q1 = *(const f32x2*)&p1[(mi_w*32 + lt)*2];
  f32x2 q2 = *(const f32x2*)&p2[(mi_w*32 + lt)*2];
  float S1 = q1[0] + q1[1], S2 = q2[0] + q2[1];
  float mu = S1*(1.f/64.f);
  float var = S2*(1.f/64.f) - mu*mu;
  float rs = rsqrtf(var + 1e-5f);
  {
    const float4* lng4 = (const float4*)lng;
    const float4* lnb4 = (const float4*)lnb;
    float* ob = out + ((size_t)(b*22 + m0 + mi_w)*64 + 32*ch)*32;
    #pragma unroll
    for (int q=0;q<4;q++){
      float4 g4 = lng4[8*ch + 2*q + hi];
      float4 b4 = lnb4[8*ch + 2*q + hi];
      float gg[4] = {g4.x,g4.y,g4.z,g4.w};
      float bg[4] = {b4.x,b4.y,b4.z,b4.w};
      #pragma unroll
      for (int e=0;e<4;e++){
        int orow = 8*q + 4*hi + e;
        ob[orow*32 + lt] = (y[4*q+e]-mu)*rs*gg[e] + bg[e];
      }
    }
  }
}

extern "C" void kernel_launch(void* const* d_in, const int* in_sizes, int n_in,
                              void* d_out, int out_size, void* d_ws, size_t ws_size,
                              hipStream_t stream){
  const float* x     = (const float*)d_in[0];
  const float* U1    = (const float*)d_in[1];
  const float* U2    = (const float*)d_in[2];
  const float* U3    = (const float*)d_in[3];
  const float* be    = (const float*)d_in[4];
  const float* Ve    = (const float*)d_in[5];
  const float* W1    = (const float*)d_in[6];
  const float* W2    = (const float*)d_in[7];
  const float* W3    = (const float*)d_in[8];
  const float* bs    = (const float*)d_in[9];
  const float* Vs    = (const float*)d_in[10];
  const float* Theta = (const float*)d_in[11];
  const float* emb   = (const float*)d_in[12];
  const float* tw    = (const float*)d_in[13];
  const float* tb    = (const float*)d_in[14];
  const float* rw    = (const float*)d_in[15];
  const float* rb    = (const float*)d_in[16];
  const float* lng   = (const float*)d_in[17];
  const float* lnb   = (const float*)d_in[18];
  float* out = (float*)d_out;
  float* wsf = (float*)d_ws;
  float* wsT   = wsf;                        // 1024 floats
  float* snorm = wsf + 1024;                 // 495616 floats
  u16*   thA   = (u16*)(wsf + 496640);       // 6144 u16
  u16*   wA    = (u16*)(wsf + 499712);       // 14336 u16
  float* wsB   = wsf + 506880;               // 64 floats
  float* smG   = wsf + 507904;               // 1024*1024
  float* xw3G  = wsf + 1556480;              // 1024*704
  float* w1eG  = wsf + 2277376;              // 1024*32

  k_attnA<<<1066, 512, 0, stream>>>(x, U1,U2,U3, be,Ve, W1, W3, smG, w1eG, xw3G,
                                    emb, wsT, Theta, tw, tb, rw, rb, thA, wA, wsB);
  k_attnB<<<1024, 512, 0, stream>>>(x, W2, bs, Vs, smG, w1eG, xw3G, snorm);
  k_fused<<<1024*11, 256, 0, stream>>>(x, wsT, snorm, thA, wA, wsB, lng, lnb, out);
}